// Round 7
// baseline (55.088 us; speedup 1.0000x reference)
//
#include <hip/hip_runtime.h>

// StatefulFormantFilter: B=32, T=48000, F=5
// y[t] = x[t] + 2 r cos(th) y[t-1] - r^2 y[t-2],  r=exp(-pi bw/SR), th=2 pi cf/SR
// x = excitation * (1-r^2) sin(th);  out = sum_f y;  new_states = (y[T-1], y[T-2])
//
// R7: R6 dataflow + LDS-staged inputs (dense float4 global loads, strided
// reads served from LDS instead of L1):
// K1: block=(b, 64-chunk group): stage 1024x5 cf/bw + 1024 exc to LDS with
//     float4; per-(chunk,f) thread builds chunk map from LDS; wave-per-formant
//     scan (smaps unions with stage buffer) -> scanned maps to Aws + group
//     product to Gprod.
// K2: per chain: wave-scan over NG=47 group products -> Sg + new_states.
// K3: same staging; entering state = Aws[c-1](Sg); replay 16 steps from LDS,
//     y overwrites cf slots in place; f-sum from LDS; coalesced stores.

constexpr int B = 32;
constexpr int T = 48000;
constexpr int F = 5;
constexpr int L = 16;          // chunk length
constexpr int C = T / L;       // 3000 chunks per chain
constexpr int GS = 64;         // chunks per group (one wave per formant)
constexpr int NG = (C + GS - 1) / GS;  // 47 groups
constexpr int NCHAIN = B * F;  // 160
constexpr int THREADS = GS * F;        // 320 = 5 waves
constexpr int MSTRIDE = 7;             // LDS map stride (7 coprime 32)
constexpr int MROW = GS * MSTRIDE;     // 448 floats per formant row

constexpr int CF_STRIDE = L * F + 4;   // 84 floats/chunk (80 data + 4 pad, 16B-aligned)
constexpr int EX_STRIDE = L + 4;       // 20 floats/chunk (16 data + 4 pad)

#define CBW2 (-9.4416635e-05f)   // -pi/(48000*ln2)
#define CCF  (1.3089969e-04f)    // 2*pi/48000

__device__ __forceinline__ float fast_exp2(float x) {
#if __has_builtin(__builtin_amdgcn_exp2f)
  return __builtin_amdgcn_exp2f(x);
#else
  return exp2f(x);
#endif
}

struct Stage {
  float cf[GS * CF_STRIDE];   // 5376 floats
  float bw[GS * CF_STRIDE];   // 5376 floats
  float ex[GS * EX_STRIDE];   // 1280 floats
};

// Stage one block-window (nc chunks) of cf/bw/exc into LDS, dense float4 loads.
__device__ __forceinline__ void stage_inputs(
    Stage& st, const float* __restrict__ exc, const float* __restrict__ cf,
    const float* __restrict__ bw, int b, int g, int nc, int tid) {
  size_t t0 = (size_t)g * (GS * L);
  const float4* csrc = (const float4*)(cf + ((size_t)b * T + t0) * F);
  const float4* bsrc = (const float4*)(bw + ((size_t)b * T + t0) * F);
  const float4* esrc = (const float4*)(exc + (size_t)b * T + t0);
  int nvec = nc * 20;   // 20 float4 per chunk (80 floats), chunk-aligned
  for (int k = tid; k < nvec; k += THREADS) {
    float4 v = csrc[k];
    *(float4*)&st.cf[(k / 20) * CF_STRIDE + (k % 20) * 4] = v;
  }
  for (int k = tid; k < nvec; k += THREADS) {
    float4 v = bsrc[k];
    *(float4*)&st.bw[(k / 20) * CF_STRIDE + (k % 20) * 4] = v;
  }
  int nve = nc * 4;     // 4 float4 per chunk (16 floats)
  for (int k = tid; k < nve; k += THREADS) {
    float4 v = esrc[k];
    *(float4*)&st.ex[(k / 4) * EX_STRIDE + (k % 4) * 4] = v;
  }
}

// Inclusive Hillis-Steele scan of affine maps across a wave (newest-on-left).
__device__ __forceinline__ void wave_scan_maps(int lane, float& u1, float& u2,
                                               float& v1, float& v2,
                                               float& w1, float& w2) {
  #pragma unroll
  for (int d = 1; d < 64; d <<= 1) {
    float pu1 = __shfl_up(u1, d);
    float pv1 = __shfl_up(v1, d);
    float pu2 = __shfl_up(u2, d);
    float pv2 = __shfl_up(v2, d);
    float pw1 = __shfl_up(w1, d);
    float pw2 = __shfl_up(w2, d);
    bool has = (lane >= d);
    pu1 = has ? pu1 : 1.f;  pv1 = has ? pv1 : 0.f;
    pu2 = has ? pu2 : 0.f;  pv2 = has ? pv2 : 1.f;
    pw1 = has ? pw1 : 0.f;  pw2 = has ? pw2 : 0.f;
    float nu1 = fmaf(u1, pu1, v1 * pu2);
    float nv1 = fmaf(u1, pv1, v1 * pv2);
    float nu2 = fmaf(u2, pu1, v2 * pu2);
    float nv2 = fmaf(u2, pv1, v2 * pv2);
    float nw1 = fmaf(u1, pw1, fmaf(v1, pw2, w1));
    float nw2 = fmaf(u2, pw1, fmaf(v2, pw2, w2));
    u1 = nu1; v1 = nv1; u2 = nu2; v2 = nv2; w1 = nw1; w2 = nw2;
  }
}

union SharedK1 {
  Stage st;
  float smaps[F][MROW];
};

__global__ __launch_bounds__(THREADS) void k1_kernel(
    const float* __restrict__ exc, const float* __restrict__ cf,
    const float* __restrict__ bw, float* __restrict__ Aws,
    float* __restrict__ Gprod) {
  __shared__ SharedK1 sh;

  int bg = blockIdx.x;
  int b = bg / NG;
  int g = bg % NG;
  int c0 = g * GS;
  int nc = (C - c0 < GS) ? (C - c0) : GS;
  int tid = threadIdx.x;
  int c_local = tid / F;
  int f = tid % F;

  stage_inputs(sh.st, exc, cf, bw, b, g, nc, tid);
  __syncthreads();

  float u1 = 1.f, u2 = 0.f, v1 = 0.f, v2 = 1.f, w1 = 0.f, w2 = 0.f;
  if (c_local < nc) {
    const float* cfp = &sh.st.cf[c_local * CF_STRIDE + f];
    const float* bwp = &sh.st.bw[c_local * CF_STRIDE + f];
    const float* ep  = &sh.st.ex[c_local * EX_STRIDE];
    #pragma unroll
    for (int i = 0; i < L; ++i) {
      float bwf = bwp[i * F];
      float cff = cfp[i * F];
      float e   = ep[i];
      float r  = fast_exp2(CBW2 * bwf);
      float th = CCF * cff;
      float sn = __sinf(th);
      float cs = __cosf(th);
      float p = 2.f * r * cs;     // -a1
      float q = -r * r;           // -a2
      float gn = fmaf(q, sn, sn); // (1-r^2) sin(th)
      float x = e * gn;
      float nu = fmaf(p, u1, q * u2);
      float nv = fmaf(p, v1, q * v2);
      float nw = fmaf(p, w1, fmaf(q, w2, x));
      u2 = u1; u1 = nu;
      v2 = v1; v1 = nv;
      w2 = w1; w1 = nw;
    }
  }
  __syncthreads();   // stage buffer dead; smaps may overwrite (union)

  {
    float* m = &sh.smaps[f][c_local * MSTRIDE];
    m[0] = u1; m[1] = u2; m[2] = v1; m[3] = v2; m[4] = w1; m[5] = w2;
  }
  __syncthreads();

  int w = tid >> 6;       // wave id == formant id (0..4)
  int lane = tid & 63;    // lane == chunk within group
  const float* s = &sh.smaps[w][lane * MSTRIDE];
  float a1 = s[0], a2 = s[1], a3 = s[2], a4 = s[3], a5 = s[4], a6 = s[5];
  wave_scan_maps(lane, a1, a2, a3, a4, a5, a6);

  int c2 = c0 + lane;
  int chain = b * F + w;
  if (c2 < C) {
    float4* o = (float4*)(Aws + ((size_t)chain * C + c2) * 8);
    o[0] = make_float4(a1, a2, a3, a4);
    o[1] = make_float4(a5, a6, 0.f, 0.f);
  }
  if (lane == 63) {
    float4* gp = (float4*)(Gprod + (size_t)(chain * NG + g) * 8);
    gp[0] = make_float4(a1, a2, a3, a4);
    gp[1] = make_float4(a5, a6, 0.f, 0.f);
  }
}

__global__ __launch_bounds__(64) void k2_kernel(
    const float* __restrict__ Gprod, const float* __restrict__ states0,
    float* __restrict__ Sg, float* __restrict__ out_states) {
  int chain = blockIdx.x;
  int lane = threadIdx.x;

  float u1 = 1.f, u2 = 0.f, v1 = 0.f, v2 = 1.f, w1 = 0.f, w2 = 0.f;
  if (lane < NG) {
    const float4* gp = (const float4*)(Gprod + (size_t)(chain * NG + lane) * 8);
    float4 A0 = gp[0];
    float4 A1 = gp[1];
    u1 = A0.x; u2 = A0.y; v1 = A0.z; v2 = A0.w; w1 = A1.x; w2 = A1.y;
  }

  wave_scan_maps(lane, u1, u2, v1, v2, w1, w2);

  float s01 = states0[chain * 2 + 0];
  float s02 = states0[chain * 2 + 1];

  // exclusive prefix -> state entering group g
  float eu1 = __shfl_up(u1, 1), ev1 = __shfl_up(v1, 1);
  float eu2 = __shfl_up(u2, 1), ev2 = __shfl_up(v2, 1);
  float ew1 = __shfl_up(w1, 1), ew2 = __shfl_up(w2, 1);
  if (lane == 0) { eu1 = 1.f; ev1 = 0.f; eu2 = 0.f; ev2 = 1.f; ew1 = 0.f; ew2 = 0.f; }
  if (lane < NG) {
    float sy1 = fmaf(eu1, s01, fmaf(ev1, s02, ew1));
    float sy2 = fmaf(eu2, s01, fmaf(ev2, s02, ew2));
    *(float2*)(Sg + (size_t)(chain * NG + lane) * 2) = make_float2(sy1, sy2);
  }

  // final state (identity pads make lane63 the full product)
  float ay1 = fmaf(u1, s01, fmaf(v1, s02, w1));
  float ay2 = fmaf(u2, s01, fmaf(v2, s02, w2));
  float fy1 = __shfl(ay1, 63);
  float fy2 = __shfl(ay2, 63);
  if (lane == 0) {
    out_states[chain * 2 + 0] = fy1;
    out_states[chain * 2 + 1] = fy2;
  }
}

__global__ __launch_bounds__(THREADS) void k3_kernel(
    const float* __restrict__ exc, const float* __restrict__ cf,
    const float* __restrict__ bw, const float* __restrict__ Aws,
    const float* __restrict__ Sg, float* __restrict__ out) {
  __shared__ Stage st;

  int bg = blockIdx.x;
  int b = bg / NG;
  int g = bg % NG;
  int c0 = g * GS;
  int nc = (C - c0 < GS) ? (C - c0) : GS;
  int tid = threadIdx.x;
  int c_local = tid / F;
  int f = tid % F;

  stage_inputs(st, exc, cf, bw, b, g, nc, tid);
  __syncthreads();

  if (c_local < nc) {
    int c = c0 + c_local;
    int chain = b * F + f;

    // entering state of chunk c (Aws holds group-local inclusive maps)
    float2 sg = *(const float2*)(Sg + (size_t)(chain * NG + g) * 2);
    float y1, y2;
    if (c_local == 0) {
      y1 = sg.x;
      y2 = sg.y;
    } else {
      const float4* m = (const float4*)(Aws + ((size_t)chain * C + (c - 1)) * 8);
      float4 M0 = m[0];
      float4 M1 = m[1];
      y1 = fmaf(M0.x, sg.x, fmaf(M0.z, sg.y, M1.x));
      y2 = fmaf(M0.y, sg.x, fmaf(M0.w, sg.y, M1.y));
    }

    float* cfp = &st.cf[c_local * CF_STRIDE + f];
    const float* bwp = &st.bw[c_local * CF_STRIDE + f];
    const float* ep  = &st.ex[c_local * EX_STRIDE];

    #pragma unroll
    for (int i = 0; i < L; ++i) {
      float bwf = bwp[i * F];
      float cff = cfp[i * F];
      float e   = ep[i];
      float r  = fast_exp2(CBW2 * bwf);
      float th = CCF * cff;
      float sn = __sinf(th);
      float cs = __cosf(th);
      float p = 2.f * r * cs;
      float q = -r * r;
      float gn = fmaf(q, sn, sn);
      float x = e * gn;
      float y = fmaf(p, y1, fmaf(q, y2, x));
      cfp[i * F] = y;   // cf slot consumed; reuse as y buffer
      y2 = y1;
      y1 = y;
    }
  }
  __syncthreads();

  // f-sum from LDS, coalesced stores
  int nt = nc * L;
  size_t tbase = (size_t)b * T + (size_t)c0 * L;
  for (int t = tid; t < nt; t += THREADS) {
    const float* yrow = &st.cf[(t >> 4) * CF_STRIDE + (t & (L - 1)) * F];
    float s = yrow[0] + yrow[1] + yrow[2] + yrow[3] + yrow[4];
    out[tbase + t] = s;
  }
}

extern "C" void kernel_launch(void* const* d_in, const int* in_sizes, int n_in,
                              void* d_out, int out_size, void* d_ws, size_t ws_size,
                              hipStream_t stream) {
  const float* exc = (const float*)d_in[0];   // (B,T,1)
  const float* cf  = (const float*)d_in[1];   // (B,T,F)
  const float* bw  = (const float*)d_in[2];   // (B,T,F)
  const float* st  = (const float*)d_in[3];   // (B,F,2)
  float* out        = (float*)d_out;          // (B,T,1) then (B,F,2)
  float* out_states = out + (size_t)B * T;

  float* Aws   = (float*)d_ws;                       // NCHAIN*C*8 floats = 15.36 MB
  float* Gprod = Aws + (size_t)NCHAIN * C * 8;       // NCHAIN*NG*8 floats
  float* Sg    = Gprod + (size_t)NCHAIN * NG * 8;    // NCHAIN*NG*2 floats

  k1_kernel<<<B * NG, THREADS, 0, stream>>>(exc, cf, bw, Aws, Gprod);
  k2_kernel<<<NCHAIN, 64, 0, stream>>>(Gprod, st, Sg, out_states);
  k3_kernel<<<B * NG, THREADS, 0, stream>>>(exc, cf, bw, Aws, Sg, out);
}